// Round 10
// baseline (519.043 us; speedup 1.0000x reference)
//
#include <hip/hip_runtime.h>
#include <hip/hip_bf16.h>

#define N_PTS 1500000
#define NT_TILES (N_PTS / 16)     // 93750
#define NCHUNK (N_PTS / 32)       // 46875, exact
#define CBCH 96
#define CTCH 128
#define COCH 96
#define NB 8
#define BN_EPS 1e-5f
#define GRID3 512                 // R3's proven grid for the output pass
#define NWAVE3 (GRID3 * 4)
#define GRIDG 1024                // Gram pass grid
#define STPAD 100                 // sT row stride (floats)
#define CPAD 36                   // Gram LDS row stride (shorts): 72B rows, 8B-aligned, ~4-way max conflict

// ws float offsets
#define GSUM_OFF 0
#define GSQ_OFF 96
#define T_OFF 384                 // 8*96 floats
#define G_OFF 1280                // G[112][112] f32 = 12544 floats
#define GPITCH 112

typedef __attribute__((ext_vector_type(8))) short bf16x8;
typedef __attribute__((ext_vector_type(4))) float f32x4;

__device__ __forceinline__ short f2bf(float f) {
    __hip_bfloat16 h = __float2bfloat16(f);   // native cvt, RNE
    short s;
    __builtin_memcpy(&s, &h, sizeof(s));
    return s;
}
__device__ __forceinline__ float bf2f(short s) {
    return __uint_as_float(((unsigned)(unsigned short)s) << 16);
}

// K0: blocks 0..7 compute T[b][:] = text[b,:] @ W[96:224,:]; block 8 zeroes stats + G.
__global__ void k0_init(const float* __restrict__ text, const float* __restrict__ W,
                        float* __restrict__ ws) {
    if (blockIdx.x == NB) {
        for (int i = threadIdx.x; i < 192; i += blockDim.x) ws[i] = 0.f;
        for (int i = threadIdx.x; i < GPITCH * GPITCH; i += blockDim.x) ws[G_OFF + i] = 0.f;
        return;
    }
    int b = blockIdx.x;
    int c = threadIdx.x;
    if (c < COCH) {
        float acc = 0.f;
        #pragma unroll 8
        for (int k = 0; k < CTCH; ++k)
            acc += text[b * CTCH + k] * W[(CBCH + k) * COCH + c];
        ws[T_OFF + b * COCH + c] = acc;
    }
}

// ---------------------------------------------------------------------------
// K1G: Gram pass. Channels 0..95 = bf16(bb), 96..103 = one-hot(batch), rest 0.
// G[c1][c2] = sum_i ch_i[c1]*ch_i[c2], upper-triangle tiles only (28 of 7x7),
// 7 tiles per wave, K=32 points per chunk staged channel-major in LDS.

__device__ __forceinline__ bf16x8 read_frag(const short* sCh, int tile, int lr, int g) {
    const short* p = sCh + (tile * 16 + lr) * CPAD + g * 8;
    union { bf16x8 v; uint2 h[2]; } u;
    u.h[0] = *reinterpret_cast<const uint2*>(p);
    u.h[1] = *reinterpret_cast<const uint2*>(p + 4);
    return u.v;
}

__global__ __launch_bounds__(256, 2) void k1g(const float* __restrict__ bb,
                                              const int* __restrict__ bidx,
                                              float* __restrict__ ws) {
    __shared__ __align__(16) short sCh[112 * CPAD];   // 8064 B

    const int tid = threadIdx.x;
    const int lane = tid & 63, wv = tid >> 6;
    const int lr = lane & 15, g = lane >> 4;

    // this wave's 7 upper-triangle tile pairs (i<=j) of the 7x7 tile grid
    int pi[7], pj[7];
    {
        int rem = wv * 7, ii = 0;
        while (rem >= 7 - ii) { rem -= 7 - ii; ++ii; }
        int jj = ii + rem;
        #pragma unroll
        for (int u = 0; u < 7; ++u) {
            pi[u] = ii; pj[u] = jj;
            ++jj; if (jj == 7) { ++ii; jj = ii; }
        }
    }

    // zero the one-hot + pad channel rows once (rows 96..111, all cols)
    for (int i = tid; i < 16 * CPAD; i += blockDim.x) sCh[96 * CPAD + i] = 0;

    f32x4 acc[7];
    #pragma unroll
    for (int u = 0; u < 7; ++u) acc[u] = (f32x4)0.f;

    for (int ch = blockIdx.x; ch < NCHUNK; ch += GRIDG) {
        __syncthreads();   // previous iteration's frag reads complete
        // stage 32 points x 96 channels, transposed to channel-major bf16
        const float* src = bb + (size_t)ch * 32 * CBCH;
        #pragma unroll
        for (int i = 0; i < 3; ++i) {
            int q = tid + 256 * i;              // float4 index, 0..767
            int c = (q * 4) % CBCH, p = (q * 4) / CBCH;
            f32x4 v = *reinterpret_cast<const f32x4*>(src + q * 4);
            #pragma unroll
            for (int j = 0; j < 4; ++j)
                sCh[(c + j) * CPAD + p] = f2bf(v[j]);
        }
        // one-hot rows: thread t<32 owns point t (writes all 8 rows, no race)
        if (tid < 32) {
            int b = bidx[(size_t)ch * 32 + tid];
            #pragma unroll
            for (int bb8 = 0; bb8 < NB; ++bb8)
                sCh[(96 + bb8) * CPAD + tid] = (bb8 == b) ? (short)0x3F80 : (short)0;
        }
        __syncthreads();
        #pragma unroll
        for (int u = 0; u < 7; ++u) {
            bf16x8 fa = read_frag(sCh, pi[u], lr, g);
            bf16x8 fb = read_frag(sCh, pj[u], lr, g);
            acc[u] = __builtin_amdgcn_mfma_f32_16x16x32_bf16(fa, fb, acc[u], 0, 0, 0);
        }
    }

    // flush: D lane mapping col=lane&15, row=4*(lane>>4)+r
    #pragma unroll
    for (int u = 0; u < 7; ++u)
        #pragma unroll
        for (int r = 0; r < 4; ++r)
            atomicAdd(&ws[G_OFF + (pi[u] * 16 + 4 * g + r) * GPITCH + pj[u] * 16 + lr],
                      acc[u][r]);
}

// ---------------------------------------------------------------------------
// K_SOLVE: one block. GSUM[c] = sum_b (d_bc + n_b*T_bc),
// GSQ[c] = w~_c^T Gbb w~_c + sum_b (2*T_bc*d_bc + n_b*T_bc^2),
// d_bc = sum_k G[k][96+b]*w~[k][c].  Tile-symmetric G reads.
__global__ __launch_bounds__(384) void k_solve(const float* __restrict__ W,
                                               float* __restrict__ ws) {
    __shared__ short sW16[CBCH * COCH];   // bf16(W_top), 18 KB
    __shared__ float sQ[4][COCH];
    const int tid = threadIdx.x;
    for (int i = tid; i < CBCH * COCH; i += 384) sW16[i] = f2bf(W[i]);
    __syncthreads();

    const float* Gm = ws + G_OFF;
    const int c = tid % COCH;
    const int qq = tid / COCH;        // 0..3

    float accq = 0.f;
    for (int k = qq * 24; k < qq * 24 + 24; ++k) {
        float wk = bf2f(sW16[k * COCH + c]);
        int ti = k >> 4;
        float inner = 0.f;
        for (int k2 = 0; k2 < CBCH; ++k2) {
            int tj = k2 >> 4;
            int idx = (ti <= tj) ? (k * GPITCH + k2) : (k2 * GPITCH + k);
            inner += Gm[idx] * bf2f(sW16[k2 * COCH + c]);
        }
        accq += wk * inner;
    }
    sQ[qq][c] = accq;
    __syncthreads();

    if (tid < COCH) {
        float gsq = sQ[0][c] + sQ[1][c] + sQ[2][c] + sQ[3][c];
        float gsum = 0.f;
        #pragma unroll
        for (int b = 0; b < NB; ++b) {
            float d = 0.f;
            for (int k = 0; k < CBCH; ++k)
                d += Gm[k * GPITCH + 96 + b] * bf2f(sW16[k * COCH + c]);
            float Tc = ws[T_OFF + b * COCH + c];
            float nb = Gm[(96 + b) * GPITCH + 96 + b];
            gsum += d + nb * Tc;
            gsq  += 2.f * Tc * d + nb * Tc * Tc;
        }
        ws[GSUM_OFF + c] = gsum;
        ws[GSQ_OFF + c]  = gsq;
    }
}

// ---------------------------------------------------------------------------
// K3: output pass (R3 verbatim): swapped MFMA, scale/bias from GSUM/GSQ in
// prologue, reverse tile order (harvest k1g's L3-resident backbone tail), NT stores.

__device__ __forceinline__ void stage_W(const float* __restrict__ W, short* sW) {
    for (int i = threadIdx.x; i < CBCH * COCH; i += blockDim.x) {
        int k = i / COCH, c = i % COCH;
        int ct = c >> 4, lr = c & 15;
        int kt = k >> 5, grp = (k >> 3) & 3, j = k & 7;
        sW[(((ct * 3 + kt) * 64) + (grp * 16 + lr)) * 8 + j] = f2bf(W[i]);
    }
}

__device__ __forceinline__ void load_bfrag_lds(const short* sW, int lane, bf16x8 bf[6][3]) {
    #pragma unroll
    for (int ct = 0; ct < 6; ++ct)
        #pragma unroll
        for (int kt = 0; kt < 3; ++kt)
            bf[ct][kt] = *reinterpret_cast<const bf16x8*>(sW + ((ct * 3 + kt) * 64 + lane) * 8);
}

__global__ __launch_bounds__(256, 2) void k3_out(const float* __restrict__ bb,
                                                 const int* __restrict__ bidx,
                                                 const float* __restrict__ W,
                                                 const float* __restrict__ gamma,
                                                 const float* __restrict__ beta,
                                                 const float* __restrict__ ws,
                                                 float* __restrict__ out) {
    __shared__ __align__(16) short sW[6 * 3 * 64 * 8];
    __shared__ __align__(16) float sT[NB * STPAD];
    __shared__ __align__(16) float sScale[COCH];
    __shared__ __align__(16) float sBias[COCH];

    stage_W(W, sW);
    for (int i = threadIdx.x; i < NB * COCH; i += blockDim.x)
        sT[(i / COCH) * STPAD + (i % COCH)] = ws[T_OFF + i];
    if (threadIdx.x < COCH) {
        int c = threadIdx.x;
        float mean = ws[GSUM_OFF + c] * (1.f / (float)N_PTS);
        float var  = ws[GSQ_OFF + c] * (1.f / (float)N_PTS) - mean * mean;
        float scl  = gamma[c] * rsqrtf(var + BN_EPS);
        sScale[c] = scl;
        sBias[c]  = beta[c] - mean * scl;
    }
    __syncthreads();

    const int lane = threadIdx.x & 63;
    const int wv = threadIdx.x >> 6;
    const int grp = lane >> 4, lr = lane & 15;

    bf16x8 bf[6][3];
    load_bfrag_lds(sW, lane, bf);

    f32x4 sc[6], bs[6];
    #pragma unroll
    for (int ct = 0; ct < 6; ++ct) {
        sc[ct] = *reinterpret_cast<const f32x4*>(&sScale[ct * 16 + grp * 4]);
        bs[ct] = *reinterpret_cast<const f32x4*>(&sBias[ct * 16 + grp * 4]);
    }

    const int gw = blockIdx.x * 4 + wv;
    for (int t = NT_TILES - 1 - gw; t >= 0; t -= NWAVE3) {
        int base = t * 16;
        int b = bidx[base + lr];
        f32x4 acc[6];
        #pragma unroll
        for (int ct = 0; ct < 6; ++ct)
            acc[ct] = *reinterpret_cast<const f32x4*>(&sT[b * STPAD + ct * 16 + grp * 4]);

        bf16x8 pf[3];
        #pragma unroll
        for (int kt = 0; kt < 3; ++kt) {
            const f32x4* p = reinterpret_cast<const f32x4*>(bb + (size_t)(base + lr) * CBCH + kt * 32 + grp * 8);
            f32x4 x0 = p[0], x1 = p[1];
            #pragma unroll
            for (int j = 0; j < 4; ++j) {
                pf[kt][j]     = f2bf(x0[j]);
                pf[kt][4 + j] = f2bf(x1[j]);
            }
        }
        #pragma unroll
        for (int ct = 0; ct < 6; ++ct)
            #pragma unroll
            for (int kt = 0; kt < 3; ++kt)
                acc[ct] = __builtin_amdgcn_mfma_f32_16x16x32_bf16(bf[ct][kt], pf[kt], acc[ct], 0, 0, 0);

        #pragma unroll
        for (int ct = 0; ct < 6; ++ct) {
            f32x4 y;
            #pragma unroll
            for (int r = 0; r < 4; ++r)
                y[r] = fmaxf(acc[ct][r] * sc[ct][r] + bs[ct][r], 0.f);
            __builtin_nontemporal_store(y,
                reinterpret_cast<f32x4*>(out + (size_t)(base + lr) * COCH + ct * 16 + grp * 4));
        }
    }
}

extern "C" void kernel_launch(void* const* d_in, const int* in_sizes, int n_in,
                              void* d_out, int out_size, void* d_ws, size_t ws_size,
                              hipStream_t stream) {
    const float* bb    = (const float*)d_in[0];
    const int*   bidx  = (const int*)d_in[1];
    const float* text  = (const float*)d_in[2];
    const float* W     = (const float*)d_in[3];
    const float* gamma = (const float*)d_in[4];
    const float* beta  = (const float*)d_in[5];
    float* out = (float*)d_out;
    float* ws  = (float*)d_ws;

    hipLaunchKernelGGL(k0_init, dim3(NB + 1), dim3(128), 0, stream, text, W, ws);
    hipLaunchKernelGGL(k1g, dim3(GRIDG), dim3(256), 0, stream, bb, bidx, ws);
    hipLaunchKernelGGL(k_solve, dim3(1), dim3(384), 0, stream, W, ws);
    hipLaunchKernelGGL(k3_out, dim3(GRID3), dim3(256), 0, stream, bb, bidx, W, gamma, beta, ws, out);
}

// Round 11
// 442.034 us; speedup vs baseline: 1.1742x; 1.1742x over previous
//
#include <hip/hip_runtime.h>
#include <hip/hip_bf16.h>

#define N_PTS 1500000
#define NT_TILES (N_PTS / 16)   // 93750, exact
#define CBCH 96
#define CTCH 128
#define COCH 96
#define NB 8
#define BN_EPS 1e-5f
#define GRID1 1024              // 4 blocks/CU co-resident (LDS 23KB*4 < 160KB)
#define NWAVE (GRID1 * 4)
#define STPAD 100               // sT row stride (floats)

// ws float offsets
#define GSUM_OFF 0
#define GSQ_OFF 96
#define T_OFF 384   // 8*96 = 768 floats

typedef __attribute__((ext_vector_type(8))) short bf16x8;
typedef __attribute__((ext_vector_type(4))) float f32x4;

__device__ __forceinline__ short f2bf(float f) {
    __hip_bfloat16 h = __float2bfloat16(f);   // native cvt, RNE
    short s;
    __builtin_memcpy(&s, &h, sizeof(s));
    return s;
}

// K0: blocks 0..7 compute T[b][:] = text[b,:] @ W[96:224,:]; block 8 zeroes stats.
__global__ void k0_init(const float* __restrict__ text, const float* __restrict__ W,
                        float* __restrict__ ws) {
    if (blockIdx.x == NB) {
        for (int i = threadIdx.x; i < 192; i += blockDim.x) ws[i] = 0.f;
        return;
    }
    int b = blockIdx.x;
    int c = threadIdx.x;
    if (c < COCH) {
        float acc = 0.f;
        #pragma unroll 8
        for (int k = 0; k < CTCH; ++k)
            acc += text[b * CTCH + k] * W[(CBCH + k) * COCH + c];
        ws[T_OFF + b * COCH + c] = acc;
    }
}

// ---------------------------------------------------------------------------
// MFMA 16x16x32 bf16, swapped form: A = W^T frag (row=channel), B = points
// (col=point). Lane (grp=l>>4, lr=l&15) owns channels ct*16+grp*4+[0..3] of
// point base+lr.
//
// K-PERMUTATION (verified R7): fragment position (grp, j) holds
//   k_eff = kt*32 + (j<4 ? grp*4+j : 16+grp*4+(j-4))
// applied to BOTH operands -> contraction unchanged. Point-side loads become
// float4 at row*384B + kt*128B + grp*16B (+64B): each instruction's 64 lanes
// cover complete 64B lines (100% coverage, half the TA line-transactions).

__device__ __forceinline__ void stage_W(const float* __restrict__ W, short* sW) {
    for (int i = threadIdx.x; i < CBCH * COCH; i += blockDim.x) {
        int k = i / COCH, c = i % COCH;               // W[k][c], coalesced read
        int ct = c >> 4, lr = c & 15;
        int kt = k >> 5, r5 = k & 31;
        int grp = (r5 & 15) >> 2;
        int j = (r5 & 3) + ((r5 >> 4) << 2);          // r5<16 -> j=0..3 ; r5>=16 -> j=4..7
        sW[(((ct * 3 + kt) * 64) + (grp * 16 + lr)) * 8 + j] = f2bf(W[i]);
    }
}

__device__ __forceinline__ void load_bfrag_lds(const short* sW, int lane, bf16x8 bf[6][3]) {
    #pragma unroll
    for (int ct = 0; ct < 6; ++ct)
        #pragma unroll
        for (int kt = 0; kt < 3; ++kt)
            bf[ct][kt] = *reinterpret_cast<const bf16x8*>(sW + ((ct * 3 + kt) * 64 + lane) * 8);
}

// One 16-point tile: gather T[bidx] into acc, dense-load + convert, 18 MFMAs.
__device__ __forceinline__ void tile_acc(const float* __restrict__ bb,
                                         const int* __restrict__ bidx,
                                         const float* __restrict__ sT,
                                         const bf16x8 bf[6][3],
                                         int base, int grp, int lr,
                                         f32x4 acc[6]) {
    int b = bidx[base + lr];
    #pragma unroll
    for (int ct = 0; ct < 6; ++ct)
        acc[ct] = *reinterpret_cast<const f32x4*>(&sT[b * STPAD + ct * 16 + grp * 4]);

    // dense loads: float4 at row*96 + kt*32 + grp*4 and +16 (floats)
    const f32x4* q = reinterpret_cast<const f32x4*>(bb + (size_t)(base + lr) * CBCH + grp * 4);
    bf16x8 pf[3];
    #pragma unroll
    for (int kt = 0; kt < 3; ++kt) {
        f32x4 x0 = q[kt * 8];        // k_eff = kt*32 + grp*4 + {0..3}
        f32x4 x1 = q[kt * 8 + 4];    // k_eff = kt*32 + 16 + grp*4 + {0..3}
        #pragma unroll
        for (int j = 0; j < 4; ++j) {
            pf[kt][j]     = f2bf(x0[j]);
            pf[kt][4 + j] = f2bf(x1[j]);
        }
    }
    #pragma unroll
    for (int ct = 0; ct < 6; ++ct)
        #pragma unroll
        for (int kt = 0; kt < 3; ++kt)
            acc[ct] = __builtin_amdgcn_mfma_f32_16x16x32_bf16(bf[ct][kt], pf[kt], acc[ct], 0, 0, 0);
}

// K1: stats pass — compute x, accumulate per-channel sum & sumsq, discard x.
__global__ __launch_bounds__(256, 2) void k1_stats(const float* __restrict__ bb,
                                                   const int* __restrict__ bidx,
                                                   const float* __restrict__ W,
                                                   float* __restrict__ ws) {
    __shared__ __align__(16) short sW[6 * 3 * 64 * 8];   // 18 KB
    __shared__ __align__(16) float sT[NB * STPAD];
    __shared__ float sredS[4][COCH];
    __shared__ float sredQ[4][COCH];

    stage_W(W, sW);
    for (int i = threadIdx.x; i < NB * COCH; i += blockDim.x)
        sT[(i / COCH) * STPAD + (i % COCH)] = ws[T_OFF + i];
    __syncthreads();

    const int lane = threadIdx.x & 63;
    const int wv = threadIdx.x >> 6;
    const int grp = lane >> 4, lr = lane & 15;

    bf16x8 bf[6][3];
    load_bfrag_lds(sW, lane, bf);

    f32x4 sum[6], sq[6];
    #pragma unroll
    for (int ct = 0; ct < 6; ++ct) { sum[ct] = (f32x4)0.f; sq[ct] = (f32x4)0.f; }

    const int gw = blockIdx.x * 4 + wv;
    for (int t = gw; t < NT_TILES; t += NWAVE) {
        int base = t * 16;
        f32x4 acc[6];
        tile_acc(bb, bidx, sT, bf, base, grp, lr, acc);
        #pragma unroll
        for (int ct = 0; ct < 6; ++ct) {
            sum[ct] += acc[ct];
            sq[ct] += acc[ct] * acc[ct];
        }
    }

    // reduce over lr (16 lanes of same grp hold same channels, different points)
    #pragma unroll
    for (int ct = 0; ct < 6; ++ct)
        #pragma unroll
        for (int r = 0; r < 4; ++r) {
            float s = sum[ct][r], q = sq[ct][r];
            s += __shfl_xor(s, 1);  q += __shfl_xor(q, 1);
            s += __shfl_xor(s, 2);  q += __shfl_xor(q, 2);
            s += __shfl_xor(s, 4);  q += __shfl_xor(q, 4);
            s += __shfl_xor(s, 8);  q += __shfl_xor(q, 8);
            if (lr == 0) {
                sredS[wv][ct * 16 + grp * 4 + r] = s;
                sredQ[wv][ct * 16 + grp * 4 + r] = q;
            }
        }
    __syncthreads();
    if (threadIdx.x < COCH) {
        int c = threadIdx.x;
        atomicAdd(&ws[GSUM_OFF + c], sredS[0][c] + sredS[1][c] + sredS[2][c] + sredS[3][c]);
        atomicAdd(&ws[GSQ_OFF + c],  sredQ[0][c] + sredQ[1][c] + sredQ[2][c] + sredQ[3][c]);
    }
}

// K3: output pass — finalize scale/bias in prologue, recompute x, normalize +
// ReLU, NT store. Reverse tile order harvests pass-1's L3-resident tail.
__global__ __launch_bounds__(256, 2) void k3_out(const float* __restrict__ bb,
                                                 const int* __restrict__ bidx,
                                                 const float* __restrict__ W,
                                                 const float* __restrict__ gamma,
                                                 const float* __restrict__ beta,
                                                 const float* __restrict__ ws,
                                                 float* __restrict__ out) {
    __shared__ __align__(16) short sW[6 * 3 * 64 * 8];
    __shared__ __align__(16) float sT[NB * STPAD];
    __shared__ __align__(16) float sScale[COCH];
    __shared__ __align__(16) float sBias[COCH];

    stage_W(W, sW);
    for (int i = threadIdx.x; i < NB * COCH; i += blockDim.x)
        sT[(i / COCH) * STPAD + (i % COCH)] = ws[T_OFF + i];
    if (threadIdx.x < COCH) {
        int c = threadIdx.x;
        float mean = ws[GSUM_OFF + c] * (1.f / (float)N_PTS);
        float var  = ws[GSQ_OFF + c] * (1.f / (float)N_PTS) - mean * mean;
        float scl  = gamma[c] * rsqrtf(var + BN_EPS);
        sScale[c] = scl;
        sBias[c]  = beta[c] - mean * scl;
    }
    __syncthreads();

    const int lane = threadIdx.x & 63;
    const int wv = threadIdx.x >> 6;
    const int grp = lane >> 4, lr = lane & 15;

    bf16x8 bf[6][3];
    load_bfrag_lds(sW, lane, bf);

    f32x4 sc[6], bs[6];
    #pragma unroll
    for (int ct = 0; ct < 6; ++ct) {
        sc[ct] = *reinterpret_cast<const f32x4*>(&sScale[ct * 16 + grp * 4]);
        bs[ct] = *reinterpret_cast<const f32x4*>(&sBias[ct * 16 + grp * 4]);
    }

    const int gw = blockIdx.x * 4 + wv;
    for (int t = NT_TILES - 1 - gw; t >= 0; t -= NWAVE) {
        int base = t * 16;
        f32x4 acc[6];
        tile_acc(bb, bidx, sT, bf, base, grp, lr, acc);
        #pragma unroll
        for (int ct = 0; ct < 6; ++ct) {
            f32x4 y;
            #pragma unroll
            for (int r = 0; r < 4; ++r)
                y[r] = fmaxf(acc[ct][r] * sc[ct][r] + bs[ct][r], 0.f);
            __builtin_nontemporal_store(y,
                reinterpret_cast<f32x4*>(out + (size_t)(base + lr) * COCH + ct * 16 + grp * 4));
        }
    }
}

extern "C" void kernel_launch(void* const* d_in, const int* in_sizes, int n_in,
                              void* d_out, int out_size, void* d_ws, size_t ws_size,
                              hipStream_t stream) {
    const float* bb    = (const float*)d_in[0];
    const int*   bidx  = (const int*)d_in[1];
    const float* text  = (const float*)d_in[2];
    const float* W     = (const float*)d_in[3];
    const float* gamma = (const float*)d_in[4];
    const float* beta  = (const float*)d_in[5];
    float* out = (float*)d_out;
    float* ws  = (float*)d_ws;

    hipLaunchKernelGGL(k0_init, dim3(NB + 1), dim3(128), 0, stream, text, W, ws);
    hipLaunchKernelGGL(k1_stats, dim3(GRID1), dim3(256), 0, stream, bb, bidx, W, ws);
    hipLaunchKernelGGL(k3_out, dim3(GRID1), dim3(256), 0, stream, bb, bidx, W, gamma, beta, ws, out);
}